// Round 14
// baseline (1516.588 us; speedup 1.0000x reference)
//
#include <hip/hip_runtime.h>
#include <hip/hip_bf16.h>
#include <math.h>

// ---------------- problem constants ----------------
#define N_INSTR   16384
#define T_TOK     16
#define N_BLOCKS  512
#define MAX_BLK   64
#define HDIM      128
#define P_INSTR   32
#define P_GLOB    8
#define D_WORD    296
#define N_TOKENS  1024

#define CIB       32      // instructions per WG (2 M-tiles of 16); grid 512 = 2 WG/CU
#define HPAD      136     // bf16 h row pad: 272B rows, 16B-aligned, ~2-way LDS banks

typedef short s16x8 __attribute__((ext_vector_type(8)));   // 8 bf16 bits (4 VGPRs)
typedef float f32x4 __attribute__((ext_vector_type(4)));

__device__ __forceinline__ float sigf(float x) {
    return 1.0f / (1.0f + __expf(-x));
}
__device__ __forceinline__ float tanhf_s(float x) {
    float a = fabsf(x);
    float e = __expf(-2.0f * a);
    float t = (1.0f - e) / (1.0f + e);
    return copysignf(t, x);
}
__device__ __forceinline__ ushort f2bf(float f) {          // RNE float->bf16 bits
    unsigned u = __float_as_uint(f);
    unsigned r = u + 0x7FFFu + ((u >> 16) & 1u);
    return (ushort)(r >> 16);
}
__device__ __forceinline__ float bf2f(ushort h) {
    return __uint_as_float(((unsigned)h) << 16);
}

// ---------------- weight packing (fp32 word path + char Wih for ex_pack) ----------------
__global__ __launch_bounds__(256) void prep_pack(
    const float* __restrict__ cWihF, const float* __restrict__ cWhhF,
    const float* __restrict__ cWihB, const float* __restrict__ cWhhB,
    const float* __restrict__ wWihF, const float* __restrict__ wWihB,
    const float* __restrict__ wWhhF, const float* __restrict__ wWhhB,
    float* __restrict__ W4cf, float* __restrict__ W4cb,
    float* __restrict__ W4p,  float* __restrict__ W4h)
{
    int idx = blockIdx.x * 256 + threadIdx.x;
    if (idx < 131072) {                       // char fwd (Wih part used by ex_pack)
        int kk = idx & 3, f = idx >> 2;
        int j = f & 511, k = ((f >> 9) << 2) + kk;
        W4cf[idx] = (k < 128) ? cWihF[j*128 + k] : cWhhF[j*128 + (k-128)];
    } else if (idx < 262144) {                // char bwd
        int id = idx - 131072;
        int kk = id & 3, f = id >> 2;
        int j = f & 511, k = ((f >> 9) << 2) + kk;
        W4cb[id] = (k < 128) ? cWihB[j*128 + k] : cWhhB[j*128 + (k-128)];
    } else if (idx < 262144 + 303104) {       // word input proj (K=296, N=1024)
        int id = idx - 262144;
        int kk = id & 3, f = id >> 2;
        int j = f & 1023, k = ((f >> 10) << 2) + kk;
        W4p[id] = (j < 512) ? wWihF[j*296 + k] : wWihB[(j-512)*296 + k];
    } else if (idx < 565248 + 131072) {       // word recurrent (K=128, N=1024)
        int id = idx - 565248;
        int kk = id & 3, f = id >> 2;
        int j = f & 1023, k = ((f >> 10) << 2) + kk;
        W4h[id] = (j < 512) ? wWhhF[j*128 + k] : wWhhB[(j-512)*128 + k];
    }
}

// ---------------- char Whh -> bf16 hi/lo MFMA B-fragments ----------------
// Fragment F = ((((dir*4+w)*4+kk)*8+j)*2+hl)*64+lane, 8 bf16 each.
// Tile n = w + 4*j covers gates [n*16, n*16+16); B[k][col]: col=lane&15,
// k = kk*32 + (lane>>4)*8 + jj.
__global__ __launch_bounds__(256) void pack_bfrag(
    const float* __restrict__ cWhhF, const float* __restrict__ cWhhB,
    ushort* __restrict__ Bf)
{
    int F = blockIdx.x * 256 + threadIdx.x;
    if (F >= 32768) return;
    int lane = F & 63; int q = F >> 6;
    int hl = q & 1; q >>= 1;
    int j  = q & 7; q >>= 3;
    int kk = q & 3; q >>= 2;
    int w  = q & 3; q >>= 2;
    int dir = q;
    const float* W = dir ? cWhhB : cWhhF;
    int n = w + 4 * j;
    int gate = n * 16 + (lane & 15);
    int k0 = kk * 32 + (lane >> 4) * 8;
    #pragma unroll
    for (int jj = 0; jj < 8; ++jj) {
        float wv = W[gate * 128 + k0 + jj];
        ushort h = f2bf(wv);
        Bf[(size_t)F * 8 + jj] = hl ? f2bf(wv - bf2f(h)) : h;
    }
}

// ---------------- block scan ----------------
__global__ __launch_bounds__(512) void scan_kernel(
    const int* __restrict__ block_lens, int* __restrict__ starts, int* __restrict__ bid)
{
    __shared__ int s[N_BLOCKS];
    int t = threadIdx.x;
    int len = block_lens[t];
    s[t] = len;
    __syncthreads();
    for (int off = 1; off < N_BLOCKS; off <<= 1) {
        int v = (t >= off) ? s[t - off] : 0;
        __syncthreads();
        s[t] += v;
        __syncthreads();
    }
    int start = s[t] - len;
    starts[t] = start;
    for (int p = 0; p < len; ++p) bid[start + p] = t;
}

// ---------------- counting sorts ----------------
__global__ __launch_bounds__(256) void sort_by_len(
    const int* __restrict__ token_lens, int* __restrict__ order)
{
    __shared__ int cnt[T_TOK + 1];
    __shared__ int base[T_TOK + 1];
    int tid = threadIdx.x;
    if (tid <= T_TOK) cnt[tid] = 0;
    __syncthreads();
    for (int i = tid; i < N_INSTR; i += 256) atomicAdd(&cnt[token_lens[i]], 1);
    __syncthreads();
    if (tid == 0) {
        int s = 0;
        for (int l = 0; l <= T_TOK; ++l) { base[l] = s; s += cnt[l]; }
    }
    __syncthreads();
    for (int i = tid; i < N_INSTR; i += 256) {
        int pos = atomicAdd(&base[token_lens[i]], 1);
        order[pos] = i;
    }
}

__global__ __launch_bounds__(512) void sort_blocks(
    const int* __restrict__ block_lens, int* __restrict__ border)
{
    __shared__ int cnt[MAX_BLK + 1];
    __shared__ int base[MAX_BLK + 1];
    int tid = threadIdx.x;
    if (tid <= MAX_BLK) cnt[tid] = 0;
    __syncthreads();
    int len = block_lens[tid];
    atomicAdd(&cnt[len], 1);
    __syncthreads();
    if (tid == 0) {
        int s = 0;
        for (int l = 0; l <= MAX_BLK; ++l) { base[l] = s; s += cnt[l]; }
    }
    __syncthreads();
    int pos = atomicAdd(&base[len], 1);
    border[pos] = tid;
}

// ---------------- E'[token] = emb@Wih^T + bias (both dirs, bias folded) ----------------
__global__ __launch_bounds__(256) void ex_pack(
    const float* __restrict__ emb,
    const float* __restrict__ W4cf, const float* __restrict__ W4cb,
    const float* __restrict__ cbF,  const float* __restrict__ cbB,
    float* __restrict__ EF4, float* __restrict__ EB4)
{
    __shared__ float xe[128];
    int tk  = blockIdx.x;
    int tid = threadIdx.x;
    if (tid < 32) ((float4*)xe)[tid] = ((const float4*)(emb + tk * HDIM))[tid];
    __syncthreads();
    int u = tid & 127, dir = tid >> 7;
    const float4* W = (const float4*)(dir ? W4cb : W4cf);   // kc 0..31 = Wih part
    const float*  B = dir ? cbB : cbF;
    float a0 = 0.f, a1 = 0.f, a2 = 0.f, a3 = 0.f;
    for (int kc = 0; kc < 32; ++kc) {
        float4 x  = ((const float4*)xe)[kc];
        float4 w0 = W[kc*512 +   0 + u];
        float4 w1 = W[kc*512 + 128 + u];
        float4 w2 = W[kc*512 + 256 + u];
        float4 w3 = W[kc*512 + 384 + u];
        a0 = fmaf(w0.x,x.x,fmaf(w0.y,x.y,fmaf(w0.z,x.z,fmaf(w0.w,x.w,a0))));
        a1 = fmaf(w1.x,x.x,fmaf(w1.y,x.y,fmaf(w1.z,x.z,fmaf(w1.w,x.w,a1))));
        a2 = fmaf(w2.x,x.x,fmaf(w2.y,x.y,fmaf(w2.z,x.z,fmaf(w2.w,x.w,a2))));
        a3 = fmaf(w3.x,x.x,fmaf(w3.y,x.y,fmaf(w3.z,x.z,fmaf(w3.w,x.w,a3))));
    }
    float4 r = make_float4(a0 + B[u], a1 + B[128+u], a2 + B[256+u], a3 + B[384+u]);
    ((float4*)(dir ? EB4 : EF4))[tk * 128 + u] = r;
}

// ---------------- char BiLSTM via MFMA (bf16 hi/lo split, fp32-equivalent) ----------------
// WG = 32 sorted instrs, 256 threads = 4 waves. Wave w owns gate tiles n=w+4j
// (j=0..7): all 4 gate types of units u in groups w,w+4 land in the SAME lane
// (gates = acc[gt*2+ug]); c-state in regs, no cross-lane pointwise traffic.
// h stored in LDS as bf16 hi+lo; 3 MFMAs/K-chunk (hh, lh, hl) => matmul error
// ~2^-16 (fp32-equivalent), no bf16 tolerance gamble.
__global__ __launch_bounds__(256, 2) void char_lstm(
    const int* __restrict__ tokens, const int* __restrict__ token_lens,
    const int* __restrict__ order,
    const float* __restrict__ EF4, const float* __restrict__ EB4,
    const ushort* __restrict__ Bfrag,
    float* __restrict__ instr_h)
{
    __shared__ ushort hhi[2][CIB][HPAD];
    __shared__ ushort hlo[2][CIB][HPAD];
    __shared__ int    toks_s[CIB][T_TOK];
    __shared__ int    lens_s[CIB];
    __shared__ int    iid[CIB];
    __shared__ int    maxl_s;

    const int tid = threadIdx.x;
    const int i0  = blockIdx.x * CIB;

    if (tid == 0) maxl_s = 0;
    __syncthreads();
    if (tid < CIB) {
        int id = order[i0 + tid];
        iid[tid] = id;
        int ln = token_lens[id];
        lens_s[tid] = ln;
        atomicMax(&maxl_s, ln);
    }
    __syncthreads();
    for (int idx = tid; idx < CIB * T_TOK; idx += 256)
        toks_s[idx >> 4][idx & 15] = tokens[iid[idx >> 4] * T_TOK + (idx & 15)];
    for (int idx = tid; idx < 2 * CIB * HPAD; idx += 256) {
        ((ushort*)hhi)[idx] = 0;
        ((ushort*)hlo)[idx] = 0;
    }
    __syncthreads();

    const int l   = tid & 63;
    const int w   = tid >> 6;
    const int col = l & 15;
    const int hi4 = l >> 4;
    const int u0  = w * 16 + col;
    const int u1  = (w + 4) * 16 + col;

    int lenr[8];
    #pragma unroll
    for (int m = 0; m < 2; ++m)
        #pragma unroll
        for (int reg = 0; reg < 4; ++reg)
            lenr[m*4 + reg] = lens_s[m*16 + hi4*4 + reg];

    float cst[2][16];
    #pragma unroll
    for (int d = 0; d < 2; ++d)
        #pragma unroll
        for (int c = 0; c < 16; ++c) cst[d][c] = 0.f;

    const s16x8* Bfv = (const s16x8*)Bfrag;
    const int maxl = maxl_s;

    for (int t = 0; t < maxl; ++t) {
        #pragma unroll
        for (int dir = 0; dir < 2; ++dir) {
            const float4* Ep = dir ? (const float4*)EB4 : (const float4*)EF4;
            f32x4 acc[2][8];
            // acc init from E-table (bias folded in)
            #pragma unroll
            for (int m = 0; m < 2; ++m) {
                #pragma unroll
                for (int reg = 0; reg < 4; ++reg) {
                    int i  = m*16 + hi4*4 + reg;
                    int ln = lenr[m*4 + reg];
                    int tt = dir ? (ln - 1 - t) : t;
                    tt = tt < 0 ? 0 : tt;
                    int tok = toks_s[i][tt];
                    float4 e0 = Ep[tok * 128 + u0];
                    float4 e1 = Ep[tok * 128 + u1];
                    acc[m][0][reg] = e0.x; acc[m][2][reg] = e0.y;
                    acc[m][4][reg] = e0.z; acc[m][6][reg] = e0.w;
                    acc[m][1][reg] = e1.x; acc[m][3][reg] = e1.y;
                    acc[m][5][reg] = e1.z; acc[m][7][reg] = e1.w;
                }
            }
            // MFMA: acc += h_hi*W_hi + h_lo*W_hi + h_hi*W_lo  (K=128 in 4 chunks)
            #pragma unroll
            for (int kk = 0; kk < 4; ++kk) {
                int cofs = kk*32 + hi4*8;
                s16x8 a0h = *(const s16x8*)&hhi[dir][col     ][cofs];
                s16x8 a0l = *(const s16x8*)&hlo[dir][col     ][cofs];
                s16x8 a1h = *(const s16x8*)&hhi[dir][16 + col][cofs];
                s16x8 a1l = *(const s16x8*)&hlo[dir][16 + col][cofs];
                const s16x8* bp = Bfv + (size_t)(((dir*4 + w)*4 + kk)) * 1024;
                #pragma unroll
                for (int j = 0; j < 8; ++j) {
                    s16x8 bh = bp[(2*j + 0)*64 + l];
                    s16x8 bl = bp[(2*j + 1)*64 + l];
                    acc[0][j] = __builtin_amdgcn_mfma_f32_16x16x32_bf16(a0h, bh, acc[0][j], 0, 0, 0);
                    acc[0][j] = __builtin_amdgcn_mfma_f32_16x16x32_bf16(a0l, bh, acc[0][j], 0, 0, 0);
                    acc[0][j] = __builtin_amdgcn_mfma_f32_16x16x32_bf16(a0h, bl, acc[0][j], 0, 0, 0);
                    acc[1][j] = __builtin_amdgcn_mfma_f32_16x16x32_bf16(a1h, bh, acc[1][j], 0, 0, 0);
                    acc[1][j] = __builtin_amdgcn_mfma_f32_16x16x32_bf16(a1l, bh, acc[1][j], 0, 0, 0);
                    acc[1][j] = __builtin_amdgcn_mfma_f32_16x16x32_bf16(a1h, bl, acc[1][j], 0, 0, 0);
                }
            }
            __syncthreads();   // all waves' h reads done before pointwise writes
            // pointwise LSTM update for this lane's 16 (instr,u) cells
            #pragma unroll
            for (int m = 0; m < 2; ++m) {
                #pragma unroll
                for (int ug = 0; ug < 2; ++ug) {
                    #pragma unroll
                    for (int reg = 0; reg < 4; ++reg) {
                        int i = m*16 + hi4*4 + reg;
                        if (t < lenr[m*4 + reg]) {
                            float gi = sigf   (acc[m][0 + ug][reg]);
                            float gf = sigf   (acc[m][2 + ug][reg]);
                            float gg = tanhf_s(acc[m][4 + ug][reg]);
                            float go = sigf   (acc[m][6 + ug][reg]);
                            int ci = m*8 + ug*4 + reg;
                            float cn = gf * cst[dir][ci] + gi * gg;
                            cst[dir][ci] = cn;
                            float h = go * tanhf_s(cn);
                            ushort hh = f2bf(h);
                            int uu = ug ? u1 : u0;
                            hhi[dir][i][uu] = hh;
                            hlo[dir][i][uu] = f2bf(h - bf2f(hh));
                        }
                    }
                }
            }
            __syncthreads();   // h writes visible before next phase's A reads
        }
    }

    // final h = hi + lo (error ~2^-16), write at ORIGINAL instruction ids
    for (int idx = tid; idx < CIB * 128; idx += 256) {
        int i = idx >> 7, uu = idx & 127;
        int id = iid[i];
        instr_h[id * 256 +       uu] = bf2f(hhi[0][i][uu]) + bf2f(hlo[0][i][uu]);
        instr_h[id * 256 + 128 + uu] = bf2f(hhi[1][i][uu]) + bf2f(hlo[1][i][uu]);
    }
}

// ---------------- gather word inputs xw[i][296] ----------------
__global__ __launch_bounds__(256) void xw_gather(
    const float* __restrict__ instr_h, const float* __restrict__ instr_params,
    const float* __restrict__ gparams, const int* __restrict__ bid,
    float* __restrict__ xw)
{
    int idx = blockIdx.x * 256 + threadIdx.x;
    if (idx >= N_INSTR * 74) return;
    int i = idx / 74, c = idx % 74;
    float4 v;
    if (c < 64)      v = ((const float4*)(instr_h + i*256))[c];
    else if (c < 72) v = ((const float4*)(instr_params + i*32))[c - 64];
    else             v = ((const float4*)(gparams + bid[i]*8))[c - 72];
    ((float4*)(xw + i*296))[c] = v;
}

// ---------------- word input projection ----------------
__global__ __launch_bounds__(256) void word_proj(
    const float* __restrict__ xw, const float* __restrict__ W4p,
    const float* __restrict__ b_f, const float* __restrict__ b_b,
    float* __restrict__ P)
{
    __shared__ float xs[16][296];
    int tid = threadIdx.x;
    int rowTile = blockIdx.x >> 2;
    int colTile = blockIdx.x & 3;
    int i0 = rowTile * 16;

    for (int idx = tid; idx < 16 * 74; idx += 256) {
        int i = idx / 74, c = idx % 74;
        ((float4*)&xs[i][0])[c] = ((const float4*)(xw + (size_t)(i0 + i) * 296))[c];
    }
    __syncthreads();

    int j = colTile * 256 + tid;
    float acc[16];
    #pragma unroll
    for (int i = 0; i < 16; ++i) acc[i] = 0.f;
    const float4* W4 = (const float4*)W4p;
    for (int kc = 0; kc < 74; ++kc) {
        float4 w = W4[kc*1024 + j];
        #pragma unroll
        for (int i = 0; i < 16; ++i) {
            float4 x = ((const float4*)&xs[i][0])[kc];
            acc[i] = fmaf(w.x,x.x,fmaf(w.y,x.y,fmaf(w.z,x.z,fmaf(w.w,x.w,acc[i]))));
        }
    }
    float bias = (j < 512) ? b_f[j] : b_b[j - 512];
    for (int i = 0; i < 16; ++i)
        P[(size_t)(i0 + i) * 1024 + j] = acc[i] + bias;
}

// ---------------- word BiLSTM, fully fused ----------------
__global__ __launch_bounds__(256, 2) void word_lstm(
    const float* __restrict__ W4h, const float* __restrict__ P,
    const int* __restrict__ starts, const int* __restrict__ block_lens,
    const int* __restrict__ border,
    float* __restrict__ hfin)
{
    __shared__ float hs[4][128];
    __shared__ int   binfo[4][3];

    const int w   = blockIdx.x;
    const int d   = w & 1;
    const int g   = w >> 1;
    const int tid = threadIdx.x;
    const int u    = tid & 127;
    const int half = tid >> 7;
    const int q0   = half * 2;

    if (tid < 4) {
        int ob = border[g * 4 + tid];
        binfo[tid][0] = ob;
        binfo[tid][1] = starts[ob];
        binfo[tid][2] = block_lens[ob];
    }
    for (int idx = tid; idx < 4 * 128; idx += 256) ((float*)hs)[idx] = 0.f;
    __syncthreads();

    const int len0 = binfo[q0][2],     len1 = binfo[q0 + 1][2];
    const int st0  = binfo[q0][1],     st1  = binfo[q0 + 1][1];
    const int maxlen = max(max(binfo[0][2], binfo[1][2]),
                           max(binfo[2][2], binfo[3][2]));

    float c0 = 0.f, c1 = 0.f;
    const float4* W4 = (const float4*)W4h;

    for (int t = 0; t < maxlen; ++t) {
        float a0[4] = {0.f, 0.f, 0.f, 0.f};
        float a1[4] = {0.f, 0.f, 0.f, 0.f};
        for (int kc = 0; kc < 32; ++kc) {
            float4 w0 = W4[kc*1024 + d*512 +   0 + u];
            float4 w1 = W4[kc*1024 + d*512 + 128 + u];
            float4 w2 = W4[kc*1024 + d*512 + 256 + u];
            float4 w3 = W4[kc*1024 + d*512 + 384 + u];
            float4 h0 = *(const float4*)&hs[q0][kc*4];
            float4 h1 = *(const float4*)&hs[q0 + 1][kc*4];
            a0[0] = fmaf(w0.x,h0.x,fmaf(w0.y,h0.y,fmaf(w0.z,h0.z,fmaf(w0.w,h0.w,a0[0]))));
            a0[1] = fmaf(w1.x,h0.x,fmaf(w1.y,h0.y,fmaf(w1.z,h0.z,fmaf(w1.w,h0.w,a0[1]))));
            a0[2] = fmaf(w2.x,h0.x,fmaf(w2.y,h0.y,fmaf(w2.z,h0.z,fmaf(w2.w,h0.w,a0[2]))));
            a0[3] = fmaf(w3.x,h0.x,fmaf(w3.y,h0.y,fmaf(w3.z,h0.z,fmaf(w3.w,h0.w,a0[3]))));
            a1[0] = fmaf(w0.x,h1.x,fmaf(w0.y,h1.y,fmaf(w0.z,h1.z,fmaf(w0.w,h1.w,a1[0]))));
            a1[1] = fmaf(w1.x,h1.x,fmaf(w1.y,h1.y,fmaf(w1.z,h1.z,fmaf(w1.w,h1.w,a1[1]))));
            a1[2] = fmaf(w2.x,h1.x,fmaf(w2.y,h1.y,fmaf(w2.z,h1.z,fmaf(w2.w,h1.w,a1[2]))));
            a1[3] = fmaf(w3.x,h1.x,fmaf(w3.y,h1.y,fmaf(w3.z,h1.z,fmaf(w3.w,h1.w,a1[3]))));
        }
        __syncthreads();
        if (t < len0) {
            int rs = (d == 0) ? (st0 + t) : (st0 + len0 - 1 - t);
            const float* Prow = P + (size_t)rs * 1024 + d * 512;
            float gi = sigf   (a0[0] + Prow[  0 + u]);
            float gf = sigf   (a0[1] + Prow[128 + u]);
            float gg = tanhf_s(a0[2] + Prow[256 + u]);
            float go = sigf   (a0[3] + Prow[384 + u]);
            float cn = gf * c0 + gi * gg;
            c0 = cn;
            hs[q0][u] = go * tanhf_s(cn);
        }
        if (t < len1) {
            int rs = (d == 0) ? (st1 + t) : (st1 + len1 - 1 - t);
            const float* Prow = P + (size_t)rs * 1024 + d * 512;
            float gi = sigf   (a1[0] + Prow[  0 + u]);
            float gf = sigf   (a1[1] + Prow[128 + u]);
            float gg = tanhf_s(a1[2] + Prow[256 + u]);
            float go = sigf   (a1[3] + Prow[384 + u]);
            float cn = gf * c1 + gi * gg;
            c1 = cn;
            hs[q0 + 1][u] = go * tanhf_s(cn);
        }
        __syncthreads();
    }

    hfin[(size_t)(d * 512 + binfo[q0][0])     * 128 + u] = hs[q0][u];
    hfin[(size_t)(d * 512 + binfo[q0 + 1][0]) * 128 + u] = hs[q0 + 1][u];
}

// ---------------- final linear ----------------
__global__ __launch_bounds__(256) void final_k(
    const float* __restrict__ hfinal, const float* __restrict__ gp,
    const float* __restrict__ fW, const float* __restrict__ fb,
    float* __restrict__ out)
{
    int tid = threadIdx.x;
    int w = tid >> 6, l = tid & 63;
    int b = blockIdx.x * 4 + w;
    const float* hf = hfinal + (size_t)(0 * 512 + b) * 128;
    const float* hb = hfinal + (size_t)(1 * 512 + b) * 128;
    float s = hf[l] * fW[l] + hf[l + 64] * fW[l + 64]
            + hb[l] * fW[128 + l] + hb[l + 64] * fW[192 + l];
    if (l < 8) s += gp[b * 8 + l] * fW[256 + l];
    #pragma unroll
    for (int off = 32; off > 0; off >>= 1) s += __shfl_down(s, off);
    if (l == 0) out[b] = s + fb[0];
}

// ---------------- launcher ----------------
extern "C" void kernel_launch(void* const* d_in, const int* in_sizes, int n_in,
                              void* d_out, int out_size, void* d_ws, size_t ws_size,
                              hipStream_t stream)
{
    const int*   tokens        = (const int*)  d_in[0];
    const int*   token_lens    = (const int*)  d_in[1];
    const int*   block_lens    = (const int*)  d_in[2];
    const float* instr_params  = (const float*)d_in[3];
    const float* global_params = (const float*)d_in[4];
    const float* emb           = (const float*)d_in[5];
    const float* cWihF = (const float*)d_in[6];
    const float* cWhhF = (const float*)d_in[7];
    const float* cbF   = (const float*)d_in[8];
    const float* cWihB = (const float*)d_in[9];
    const float* cWhhB = (const float*)d_in[10];
    const float* cbB   = (const float*)d_in[11];
    const float* wWihF = (const float*)d_in[12];
    const float* wWhhF = (const float*)d_in[13];
    const float* wbF   = (const float*)d_in[14];
    const float* wWihB = (const float*)d_in[15];
    const float* wWhhB = (const float*)d_in[16];
    const float* wbB   = (const float*)d_in[17];
    const float* fW    = (const float*)d_in[18];
    const float* fb    = (const float*)d_in[19];
    float* out = (float*)d_out;

    char* ws = (char*)d_ws;
    size_t off = 0;
    auto alloc_f = [&](size_t nfloats) { float* p = (float*)(ws + off); off += nfloats * 4; return p; };

    float* W4cf    = alloc_f(131072);
    float* W4cb    = alloc_f(131072);
    float* W4p     = alloc_f(303104);
    float* W4h     = alloc_f(131072);
    float* Bfrag   = alloc_f(131072);               // 262144 bf16 hi/lo char Whh fragments
    float* instr_h = alloc_f((size_t)N_INSTR * 256);
    float* xw      = alloc_f((size_t)N_INSTR * 296);
    float* P       = alloc_f((size_t)N_INSTR * 1024);
    float* hfin    = alloc_f(2 * 512 * 128);
    float* EF4     = alloc_f((size_t)N_TOKENS * 128 * 4);
    float* EB4     = alloc_f((size_t)N_TOKENS * 128 * 4);
    int*   starts  = (int*)(ws + off); off += 512 * 4;
    int*   bid     = (int*)(ws + off); off += N_INSTR * 4;
    int*   order   = (int*)(ws + off); off += N_INSTR * 4;
    int*   border  = (int*)(ws + off); off += 512 * 4;

    prep_pack<<<2720, 256, 0, stream>>>(cWihF, cWhhF, cWihB, cWhhB,
                                        wWihF, wWihB, wWhhF, wWhhB,
                                        W4cf, W4cb, W4p, W4h);
    pack_bfrag<<<128, 256, 0, stream>>>(cWhhF, cWhhB, (ushort*)Bfrag);
    scan_kernel<<<1, 512, 0, stream>>>(block_lens, starts, bid);
    sort_by_len<<<1, 256, 0, stream>>>(token_lens, order);
    sort_blocks<<<1, 512, 0, stream>>>(block_lens, border);
    ex_pack<<<N_TOKENS, 256, 0, stream>>>(emb, W4cf, W4cb, cbF, cbB, EF4, EB4);

    char_lstm<<<N_INSTR / CIB, 256, 0, stream>>>(tokens, token_lens, order,
                                                 EF4, EB4, (const ushort*)Bfrag,
                                                 instr_h);
    xw_gather<<<4736, 256, 0, stream>>>(instr_h, instr_params, global_params, bid, xw);
    word_proj<<<4096, 256, 0, stream>>>(xw, W4p, wbF, wbB, P);
    word_lstm<<<256, 256, 0, stream>>>(W4h, P, starts, block_lens, border, hfin);
    final_k<<<128, 256, 0, stream>>>(hfin, global_params, fW, fb, out);
}